// Round 13
// baseline (52.393 us; speedup 1.0000x reference)
//
#include <hip/hip_runtime.h>

// X = prod_{i=0}^{n-1} (I + A_i/n), left-to-right, A: [N,2,2] f32 row-major.
// R12 post-mortem: all phase1 staging variants ~equal -> phase1 at BW floor;
// residual cost = 2 dispatch boundaries + tail kernels (~7-9us). R13: ONE
// dispatch. Blocks store partials with sc1 (agent) stores + vmcnt drain +
// relaxed agent atomic on a PER-GROUP counter (64 blocks/group -> no
// serialization hot line; R8 measured ~13ns/atomic on one line, 3907 on one
// line = 51us, 64 spread over phase1 = noise). Last arrival of each group
// tree-reduces its 64 partials; last group completion runs the 62-entry
// final. Phase1 body = R10's proven global_load_lds barrier-free version.

struct M2 { double a, b, c, d; };  // [[a,b],[c,d]]

__device__ __forceinline__ M2 m2mul(const M2& X, const M2& Y) {
    M2 r;
    r.a = fma(X.a, Y.a, X.b * Y.c);
    r.b = fma(X.a, Y.b, X.b * Y.d);
    r.c = fma(X.c, Y.a, X.d * Y.c);
    r.d = fma(X.c, Y.b, X.d * Y.d);
    return r;
}

__device__ __forceinline__ M2 from_f4(float4 v, double inv_n) {
    M2 M;
    M.a = fma((double)v.x, inv_n, 1.0);
    M.b = (double)v.y * inv_n;
    M.c = (double)v.z * inv_n;
    M.d = fma((double)v.w, inv_n, 1.0);
    return M;
}

// Ordered wave tree combine: lower lane = earlier chunk = left operand.
__device__ __forceinline__ M2 wave_combine(M2 P) {
    #pragma unroll
    for (int off = 1; off < 64; off <<= 1) {
        M2 Q;
        Q.a = __shfl_down(P.a, off);
        Q.b = __shfl_down(P.b, off);
        Q.c = __shfl_down(P.c, off);
        Q.d = __shfl_down(P.d, off);
        P = m2mul(P, Q);
    }
    return P;
}

__device__ __forceinline__ M2 load_m2_sc1(const double* p) {
    M2 Q;
    Q.a = __hip_atomic_load(p + 0, __ATOMIC_RELAXED, __HIP_MEMORY_SCOPE_AGENT);
    Q.b = __hip_atomic_load(p + 1, __ATOMIC_RELAXED, __HIP_MEMORY_SCOPE_AGENT);
    Q.c = __hip_atomic_load(p + 2, __ATOMIC_RELAXED, __HIP_MEMORY_SCOPE_AGENT);
    Q.d = __hip_atomic_load(p + 3, __ATOMIC_RELAXED, __HIP_MEMORY_SCOPE_AGENT);
    return Q;
}

__device__ __forceinline__ void store_m2_sc1(double* p, const M2& P) {
    __hip_atomic_store(p + 0, P.a, __ATOMIC_RELAXED, __HIP_MEMORY_SCOPE_AGENT);
    __hip_atomic_store(p + 1, P.b, __ATOMIC_RELAXED, __HIP_MEMORY_SCOPE_AGENT);
    __hip_atomic_store(p + 2, P.c, __ATOMIC_RELAXED, __HIP_MEMORY_SCOPE_AGENT);
    __hip_atomic_store(p + 3, P.d, __ATOMIC_RELAXED, __HIP_MEMORY_SCOPE_AGENT);
}

#define CHUNK 5
#define P1_TPB 256
#define WTILE (64 * CHUNK)             // 320 matrices per wave
#define TILE (P1_TPB * CHUNK)          // 1280 matrices per block, 20 KB LDS

__global__ void __launch_bounds__(P1_TPB) prodchain_fused(
    const float4* __restrict__ A, int n, int nb, int ng,
    double* __restrict__ part, double* __restrict__ gpart,
    unsigned* __restrict__ cnt, float* __restrict__ out)
{
    __shared__ float4 tile[TILE];
    __shared__ double bl[4 * 4];
    __shared__ int role;
    const int tid = threadIdx.x;
    const int w = tid >> 6;
    const int l = tid & 63;
    const int blockStart = blockIdx.x * TILE;
    const int waveStart = blockStart + w * WTILE;
    const double inv_n = 1.0 / (double)n;

    float4* lbase = &tile[w * WTILE];

    // ---- Phase 1 (R10's proven barrier-free direct-to-LDS) ----
    if (blockStart + TILE <= n) {
        const float4* gbase = A + waveStart;
        #pragma unroll
        for (int k = 0; k < CHUNK; ++k) {
            __builtin_amdgcn_global_load_lds(
                (const __attribute__((address_space(1))) void*)(gbase + k * 64 + l),
                (__attribute__((address_space(3))) void*)(lbase + k * 64),
                16, 0, 0);
        }
        asm volatile("s_waitcnt vmcnt(0)" ::: "memory");
    } else {
        #pragma unroll
        for (int k = 0; k < CHUNK; ++k) {
            int g = waveStart + k * 64 + l;
            lbase[k * 64 + l] = (g < n) ? A[g] : make_float4(0.f, 0.f, 0.f, 0.f);
        }
        asm volatile("s_waitcnt lgkmcnt(0)" ::: "memory");
    }

    M2 P = {1.0, 0.0, 0.0, 1.0};
    {
        const float4* my = &lbase[l * CHUNK];
        #pragma unroll
        for (int j = 0; j < CHUNK; ++j)
            P = m2mul(P, from_f4(my[j], inv_n));
    }

    P = wave_combine(P);

    if (l == 0) {
        bl[4 * w + 0] = P.a;
        bl[4 * w + 1] = P.b;
        bl[4 * w + 2] = P.c;
        bl[4 * w + 3] = P.d;
    }
    __syncthreads();

    const int grp = blockIdx.x >> 6;
    if (tid == 0) {
        M2 R = { bl[0], bl[1], bl[2], bl[3] };
        #pragma unroll
        for (int w2 = 1; w2 < 4; ++w2) {
            M2 Q = { bl[4 * w2 + 0], bl[4 * w2 + 1],
                     bl[4 * w2 + 2], bl[4 * w2 + 3] };
            R = m2mul(R, Q);
        }
        // Publish partial (LLC write-through), drain, then group ticket.
        store_m2_sc1(&part[4 * blockIdx.x], R);
        asm volatile("s_waitcnt vmcnt(0)" ::: "memory");
        unsigned members = (unsigned)min(64, nb - (grp << 6));
        unsigned old = __hip_atomic_fetch_add(&cnt[grp], 1u, __ATOMIC_RELAXED,
                                              __HIP_MEMORY_SCOPE_AGENT);
        role = (old == members - 1) ? 1 : 0;
    }
    __syncthreads();

    if (!role) return;

    // ---- Group reduce: this block is the last of its 64-block group ----
    if (tid < 64) {
        int idx = (grp << 6) + l;
        M2 T = {1.0, 0.0, 0.0, 1.0};
        if (idx < nb) T = load_m2_sc1(&part[4 * idx]);
        T = wave_combine(T);

        int fin = 0;
        if (l == 0) {
            store_m2_sc1(&gpart[4 * grp], T);
            asm volatile("s_waitcnt vmcnt(0)" ::: "memory");
            unsigned old2 = __hip_atomic_fetch_add(&cnt[ng], 1u, __ATOMIC_RELAXED,
                                                   __HIP_MEMORY_SCOPE_AGENT);
            fin = (old2 == (unsigned)ng - 1) ? 1 : 0;
        }
        fin = __shfl(fin, 0);

        // ---- Final: last group completion combines all group products ----
        if (fin) {
            M2 F = {1.0, 0.0, 0.0, 1.0};
            for (int p = 0; p * 64 < ng; ++p) {       // 1 pass for ng=62
                int gi = p * 64 + l;
                M2 T2 = {1.0, 0.0, 0.0, 1.0};
                if (gi < ng) T2 = load_m2_sc1(&gpart[4 * gi]);
                T2 = wave_combine(T2);
                F = m2mul(F, T2);                     // lane 0 meaningful
            }
            if (l == 0) {
                out[0] = (float)F.a;
                out[1] = (float)F.b;
                out[2] = (float)F.c;
                out[3] = (float)F.d;
            }
        }
    }
}

extern "C" void kernel_launch(void* const* d_in, const int* in_sizes, int n_in,
                              void* d_out, int out_size, void* d_ws, size_t ws_size,
                              hipStream_t stream) {
    const float4* A = (const float4*)d_in[0];
    const int n = in_sizes[0] / 4;                    // 5,000,000 matrices
    const int nb = (n + TILE - 1) / TILE;             // 3907 blocks/partials
    const int ng = (nb + 63) / 64;                    // 62 groups

    // ws layout (all offsets within the 133KB proven in R4):
    //   part  @ 0          : nb*32 B  (125,024)
    //   cnt   @ 126,976    : (ng+1)*4 B (252)
    //   gpart @ 131,072    : ng*32 B (1,984)
    double*   part  = (double*)d_ws;
    unsigned* cnt   = (unsigned*)((char*)d_ws + 126976);
    double*   gpart = (double*)((char*)d_ws + 131072);

    hipMemsetAsync(cnt, 0, (ng + 1) * sizeof(unsigned), stream);
    prodchain_fused<<<nb, P1_TPB, 0, stream>>>(A, n, nb, ng, part, gpart,
                                               cnt, (float*)d_out);
}

// Round 14
// 36.516 us; speedup vs baseline: 1.4348x; 1.4348x over previous
//
#include <hip/hip_runtime.h>

// X = prod_{i=0}^{n-1} (I + A_i/n), left-to-right, A: [N,2,2] f32 row-major.
// R13 post-mortem: fused-kernel cost scales with TOTAL agent-scope op count
// (19.5K ops ~= 36-55us), not counter-line contention. R14: fused again but
// with 8x fewer blocks: 489 blocks, each WAVE owns 2560 contiguous matrices
// via an 8-segment double-buffered counted-vmcnt pipeline (R12's mechanism).
// Agent ops: 489*5 + 8*5 ~= 2.5K (~5us, absorbed by finish stagger).
// Hierarchy: block partial -> 64-block group (last arrival reduces) ->
// 8 groups (last arrival finals). No spinning; order-independent product.

struct M2 { double a, b, c, d; };  // [[a,b],[c,d]]

__device__ __forceinline__ M2 m2mul(const M2& X, const M2& Y) {
    M2 r;
    r.a = fma(X.a, Y.a, X.b * Y.c);
    r.b = fma(X.a, Y.b, X.b * Y.d);
    r.c = fma(X.c, Y.a, X.d * Y.c);
    r.d = fma(X.c, Y.b, X.d * Y.d);
    return r;
}

__device__ __forceinline__ M2 from_f4(float4 v, double inv_n) {
    M2 M;
    M.a = fma((double)v.x, inv_n, 1.0);
    M.b = (double)v.y * inv_n;
    M.c = (double)v.z * inv_n;
    M.d = fma((double)v.w, inv_n, 1.0);
    return M;
}

// Ordered wave tree combine: lower lane = earlier chunk = left operand.
__device__ __forceinline__ M2 wave_combine(M2 P) {
    #pragma unroll
    for (int off = 1; off < 64; off <<= 1) {
        M2 Q;
        Q.a = __shfl_down(P.a, off);
        Q.b = __shfl_down(P.b, off);
        Q.c = __shfl_down(P.c, off);
        Q.d = __shfl_down(P.d, off);
        P = m2mul(P, Q);
    }
    return P;
}

__device__ __forceinline__ M2 load_m2_sc1(const double* p) {
    M2 Q;
    Q.a = __hip_atomic_load(p + 0, __ATOMIC_RELAXED, __HIP_MEMORY_SCOPE_AGENT);
    Q.b = __hip_atomic_load(p + 1, __ATOMIC_RELAXED, __HIP_MEMORY_SCOPE_AGENT);
    Q.c = __hip_atomic_load(p + 2, __ATOMIC_RELAXED, __HIP_MEMORY_SCOPE_AGENT);
    Q.d = __hip_atomic_load(p + 3, __ATOMIC_RELAXED, __HIP_MEMORY_SCOPE_AGENT);
    return Q;
}

__device__ __forceinline__ void store_m2_sc1(double* p, const M2& P) {
    __hip_atomic_store(p + 0, P.a, __ATOMIC_RELAXED, __HIP_MEMORY_SCOPE_AGENT);
    __hip_atomic_store(p + 1, P.b, __ATOMIC_RELAXED, __HIP_MEMORY_SCOPE_AGENT);
    __hip_atomic_store(p + 2, P.c, __ATOMIC_RELAXED, __HIP_MEMORY_SCOPE_AGENT);
    __hip_atomic_store(p + 3, P.d, __ATOMIC_RELAXED, __HIP_MEMORY_SCOPE_AGENT);
}

#define CHUNK 5
#define SEG 320                        // matrices per wave-segment (5 KB)
#define NSEG 8                         // segments per wave
#define WRUN (SEG * NSEG)              // 2560 contiguous matrices per wave
#define BTILE (WRUN * 4)               // 10240 matrices per block
#define P1_TPB 256

__global__ void __launch_bounds__(P1_TPB) prodchain_fused(
    const float4* __restrict__ A, int n, int nb, int ng,
    double* __restrict__ part, double* __restrict__ gpart,
    unsigned* __restrict__ cnt, float* __restrict__ out)
{
    __shared__ float4 buf[4][2][SEG];  // 40 KB: per-wave double buffer
    __shared__ double bl[4 * 4];
    __shared__ int role;

    const int tid = threadIdx.x;
    const int w = tid >> 6;
    const int l = tid & 63;
    const long runStart = (long)blockIdx.x * BTILE + (long)w * WRUN;
    const double inv_n = 1.0 / (double)n;

    M2 W = {1.0, 0.0, 0.0, 1.0};       // wave product (lane 0 meaningful)

    if ((long)(blockIdx.x + 1) * BTILE <= n) {
        // ---- Fast path: 8-segment double-buffered counted-vmcnt pipeline.
        const float4* g0 = A + runStart;
        #pragma unroll
        for (int k = 0; k < CHUNK; ++k)
            __builtin_amdgcn_global_load_lds(
                (const __attribute__((address_space(1))) void*)(g0 + k * 64 + l),
                (__attribute__((address_space(3))) void*)(&buf[w][0][k * 64]),
                16, 0, 0);

        #pragma unroll
        for (int t = 0; t < NSEG; ++t) {
            if (t + 1 < NSEG) {
                const float4* gn = A + runStart + (t + 1) * SEG;
                float4* lb = &buf[w][(t + 1) & 1][0];
                #pragma unroll
                for (int k = 0; k < CHUNK; ++k)
                    __builtin_amdgcn_global_load_lds(
                        (const __attribute__((address_space(1))) void*)(gn + k * 64 + l),
                        (__attribute__((address_space(3))) void*)(lb + k * 64),
                        16, 0, 0);
                asm volatile("s_waitcnt vmcnt(5)" ::: "memory");  // seg t done
            } else {
                asm volatile("s_waitcnt vmcnt(0)" ::: "memory");
            }
            M2 P = {1.0, 0.0, 0.0, 1.0};
            const float4* my = &buf[w][t & 1][l * CHUNK];
            #pragma unroll
            for (int j = 0; j < CHUNK; ++j)
                P = m2mul(P, from_f4(my[j], inv_n));
            P = wave_combine(P);
            W = m2mul(W, P);           // only lane 0's W is meaningful
        }
    } else {
        // ---- Guarded tail block: serial per-segment register staging.
        for (int t = 0; t < NSEG; ++t) {
            float4* lb = &buf[w][t & 1][0];
            #pragma unroll
            for (int k = 0; k < CHUNK; ++k) {
                long g = runStart + (long)t * SEG + k * 64 + l;
                lb[k * 64 + l] = (g < n) ? A[g]
                                         : make_float4(0.f, 0.f, 0.f, 0.f);
            }
            M2 P = {1.0, 0.0, 0.0, 1.0};
            const float4* my = &lb[l * CHUNK];
            #pragma unroll
            for (int j = 0; j < CHUNK; ++j)
                P = m2mul(P, from_f4(my[j], inv_n));
            P = wave_combine(P);
            W = m2mul(W, P);
        }
    }

    if (l == 0) {
        bl[4 * w + 0] = W.a;
        bl[4 * w + 1] = W.b;
        bl[4 * w + 2] = W.c;
        bl[4 * w + 3] = W.d;
    }
    __syncthreads();

    const int grp = blockIdx.x >> 6;
    if (tid == 0) {
        M2 R = { bl[0], bl[1], bl[2], bl[3] };
        #pragma unroll
        for (int w2 = 1; w2 < 4; ++w2) {
            M2 Q = { bl[4 * w2 + 0], bl[4 * w2 + 1],
                     bl[4 * w2 + 2], bl[4 * w2 + 3] };
            R = m2mul(R, Q);
        }
        store_m2_sc1(&part[4 * blockIdx.x], R);
        asm volatile("s_waitcnt vmcnt(0)" ::: "memory");   // publish < ticket
        unsigned members = (unsigned)min(64, nb - (grp << 6));
        unsigned old = __hip_atomic_fetch_add(&cnt[grp], 1u, __ATOMIC_RELAXED,
                                              __HIP_MEMORY_SCOPE_AGENT);
        role = (old == members - 1) ? 1 : 0;
    }
    __syncthreads();

    if (!role || tid >= 64) return;

    // ---- Group reduce: last arrival of this 64-block group ----
    int gidx = (grp << 6) + l;
    M2 T = {1.0, 0.0, 0.0, 1.0};
    if (gidx < nb) T = load_m2_sc1(&part[4 * gidx]);
    T = wave_combine(T);

    int fin = 0;
    if (l == 0) {
        store_m2_sc1(&gpart[4 * grp], T);
        asm volatile("s_waitcnt vmcnt(0)" ::: "memory");
        unsigned old2 = __hip_atomic_fetch_add(&cnt[ng], 1u, __ATOMIC_RELAXED,
                                               __HIP_MEMORY_SCOPE_AGENT);
        fin = (old2 == (unsigned)ng - 1) ? 1 : 0;
    }
    fin = __shfl(fin, 0);
    if (!fin) return;

    // ---- Final: combine the ng (=8) ordered group products ----
    M2 F = {1.0, 0.0, 0.0, 1.0};
    if (l < ng) F = load_m2_sc1(&gpart[4 * l]);
    F = wave_combine(F);
    if (l == 0) {
        out[0] = (float)F.a;
        out[1] = (float)F.b;
        out[2] = (float)F.c;
        out[3] = (float)F.d;
    }
}

extern "C" void kernel_launch(void* const* d_in, const int* in_sizes, int n_in,
                              void* d_out, int out_size, void* d_ws, size_t ws_size,
                              hipStream_t stream) {
    const float4* A = (const float4*)d_in[0];
    const int n = in_sizes[0] / 4;                    // 5,000,000 matrices
    const int nb = (n + BTILE - 1) / BTILE;           // 489 blocks/partials
    const int ng = (nb + 63) / 64;                    // 8 groups

    // ws layout: part @0 (489*32 = 15,648 B); cnt @16,384 ((ng+1)*4 = 36 B);
    // gpart @16,896 (8*32 = 256 B).
    double*   part  = (double*)d_ws;
    unsigned* cnt   = (unsigned*)((char*)d_ws + 16384);
    double*   gpart = (double*)((char*)d_ws + 16896);

    hipMemsetAsync(cnt, 0, (ng + 1) * sizeof(unsigned), stream);
    prodchain_fused<<<nb, P1_TPB, 0, stream>>>(A, n, nb, ng, part, gpart,
                                               cnt, (float*)d_out);
}

// Round 15
// 28.298 us; speedup vs baseline: 1.8514x; 1.2904x over previous
//
#include <hip/hip_runtime.h>

// X = prod_{i=0}^{n-1} (I + A_i/n), left-to-right, A: [N,2,2] f32 row-major.
// R14 post-mortem: full fusion is latency-bound (few long-chain waves) —
// abandoned for good. R15: R10's proven phase1 (23.2us best) untouched;
// the TWO tail kernels merge into ONE 62-block ticketed kernel: block b
// reduces partials [64b,64b+64) coalesced, publishes sc1, one agent ticket
// (62 atomics total — negligible), last arrival combines the 62 group
// products in-wave and writes out. Dispatches 3 -> 2.

struct M2 { double a, b, c, d; };  // [[a,b],[c,d]]

__device__ __forceinline__ M2 m2mul(const M2& X, const M2& Y) {
    M2 r;
    r.a = fma(X.a, Y.a, X.b * Y.c);
    r.b = fma(X.a, Y.b, X.b * Y.d);
    r.c = fma(X.c, Y.a, X.d * Y.c);
    r.d = fma(X.c, Y.b, X.d * Y.d);
    return r;
}

__device__ __forceinline__ M2 from_f4(float4 v, double inv_n) {
    M2 M;
    M.a = fma((double)v.x, inv_n, 1.0);
    M.b = (double)v.y * inv_n;
    M.c = (double)v.z * inv_n;
    M.d = fma((double)v.w, inv_n, 1.0);
    return M;
}

// Ordered wave tree combine: lower lane = earlier chunk = left operand.
__device__ __forceinline__ M2 wave_combine(M2 P) {
    #pragma unroll
    for (int off = 1; off < 64; off <<= 1) {
        M2 Q;
        Q.a = __shfl_down(P.a, off);
        Q.b = __shfl_down(P.b, off);
        Q.c = __shfl_down(P.c, off);
        Q.d = __shfl_down(P.d, off);
        P = m2mul(P, Q);
    }
    return P;
}

__device__ __forceinline__ M2 load_m2(const double* p) {
    double2 lo = *reinterpret_cast<const double2*>(p);
    double2 hi = *reinterpret_cast<const double2*>(p + 2);
    M2 Q = { lo.x, lo.y, hi.x, hi.y };
    return Q;
}

__device__ __forceinline__ void store_m2(double* p, const M2& P) {
    *reinterpret_cast<double2*>(p)     = double2{ P.a, P.b };
    *reinterpret_cast<double2*>(p + 2) = double2{ P.c, P.d };
}

__device__ __forceinline__ M2 load_m2_sc1(const double* p) {
    M2 Q;
    Q.a = __hip_atomic_load(p + 0, __ATOMIC_RELAXED, __HIP_MEMORY_SCOPE_AGENT);
    Q.b = __hip_atomic_load(p + 1, __ATOMIC_RELAXED, __HIP_MEMORY_SCOPE_AGENT);
    Q.c = __hip_atomic_load(p + 2, __ATOMIC_RELAXED, __HIP_MEMORY_SCOPE_AGENT);
    Q.d = __hip_atomic_load(p + 3, __ATOMIC_RELAXED, __HIP_MEMORY_SCOPE_AGENT);
    return Q;
}

__device__ __forceinline__ void store_m2_sc1(double* p, const M2& P) {
    __hip_atomic_store(p + 0, P.a, __ATOMIC_RELAXED, __HIP_MEMORY_SCOPE_AGENT);
    __hip_atomic_store(p + 1, P.b, __ATOMIC_RELAXED, __HIP_MEMORY_SCOPE_AGENT);
    __hip_atomic_store(p + 2, P.c, __ATOMIC_RELAXED, __HIP_MEMORY_SCOPE_AGENT);
    __hip_atomic_store(p + 3, P.d, __ATOMIC_RELAXED, __HIP_MEMORY_SCOPE_AGENT);
}

#define CHUNK 5
#define P1_TPB 256
#define WTILE (64 * CHUNK)             // 320 matrices per wave
#define TILE (P1_TPB * CHUNK)          // 1280 matrices per block, 20 KB LDS

__global__ void __launch_bounds__(P1_TPB) prodchain_phase1(
    const float4* __restrict__ A, int n, double* __restrict__ part)
{
    __shared__ float4 tile[TILE];
    __shared__ double bl[4 * 4];
    const int tid = threadIdx.x;
    const int w = tid >> 6;
    const int l = tid & 63;
    const int blockStart = blockIdx.x * TILE;
    const int waveStart = blockStart + w * WTILE;   // this wave's 320 matrices
    const double inv_n = 1.0 / (double)n;

    float4* lbase = &tile[w * WTILE];               // wave-local LDS segment

    if (blockStart + TILE <= n) {
        // Fast path: direct HBM->LDS, wave-local, NO block barrier.
        const float4* gbase = A + waveStart;
        #pragma unroll
        for (int k = 0; k < CHUNK; ++k) {
            __builtin_amdgcn_global_load_lds(
                (const __attribute__((address_space(1))) void*)(gbase + k * 64 + l),
                (__attribute__((address_space(3))) void*)(lbase + k * 64),
                16, 0, 0);
        }
        asm volatile("s_waitcnt vmcnt(0)" ::: "memory");
    } else {
        // Guarded tail block: register staging; OOB -> identity factor.
        #pragma unroll
        for (int k = 0; k < CHUNK; ++k) {
            int g = waveStart + k * 64 + l;
            lbase[k * 64 + l] = (g < n) ? A[g] : make_float4(0.f, 0.f, 0.f, 0.f);
        }
        asm volatile("s_waitcnt lgkmcnt(0)" ::: "memory");
    }

    // Consume this wave's contiguous per-thread chunk from LDS (no barrier).
    M2 P = {1.0, 0.0, 0.0, 1.0};
    const float4* my = &lbase[l * CHUNK];
    #pragma unroll
    for (int j = 0; j < CHUNK; ++j)
        P = m2mul(P, from_f4(my[j], inv_n));

    P = wave_combine(P);

    if (l == 0) {
        bl[4 * w + 0] = P.a;
        bl[4 * w + 1] = P.b;
        bl[4 * w + 2] = P.c;
        bl[4 * w + 3] = P.d;
    }
    __syncthreads();                    // the only block-wide barrier

    if (tid == 0) {
        M2 R = { bl[0], bl[1], bl[2], bl[3] };
        #pragma unroll
        for (int w2 = 1; w2 < 4; ++w2) {
            M2 Q = { bl[4 * w2 + 0], bl[4 * w2 + 1],
                     bl[4 * w2 + 2], bl[4 * w2 + 3] };
            R = m2mul(R, Q);
        }
        store_m2(&part[4 * blockIdx.x], R);
    }
}

// ONE ticketed tail dispatch: block b reduces partials [64b, 64b+64)
// (lane-per-partial, coalesced; identity for OOB), publishes its group
// product with sc1 stores + drain + ONE agent ticket; the last-arrival
// block combines all ng group products in-wave and writes out.
__global__ void __launch_bounds__(64) prodchain_tail(
    const double* __restrict__ part, int np, int ng,
    double* __restrict__ gpart, unsigned* __restrict__ cnt,
    float* __restrict__ out)
{
    const int l = threadIdx.x;
    const int idx = blockIdx.x * 64 + l;
    M2 P = {1.0, 0.0, 0.0, 1.0};
    if (idx < np) P = load_m2(&part[4 * idx]);   // prev dispatch: plain loads

    P = wave_combine(P);

    int fin = 0;
    if (l == 0) {
        store_m2_sc1(&gpart[4 * blockIdx.x], P);
        asm volatile("s_waitcnt vmcnt(0)" ::: "memory");  // publish < ticket
        unsigned old = __hip_atomic_fetch_add(cnt, 1u, __ATOMIC_RELAXED,
                                              __HIP_MEMORY_SCOPE_AGENT);
        fin = (old == (unsigned)ng - 1) ? 1 : 0;
    }
    fin = __shfl(fin, 0);
    if (!fin) return;

    // Last arrival: combine the ng (=62) ordered group products.
    M2 F = {1.0, 0.0, 0.0, 1.0};
    if (l < ng) F = load_m2_sc1(&gpart[4 * l]);
    F = wave_combine(F);
    if (l == 0) {
        out[0] = (float)F.a;
        out[1] = (float)F.b;
        out[2] = (float)F.c;
        out[3] = (float)F.d;
    }
}

extern "C" void kernel_launch(void* const* d_in, const int* in_sizes, int n_in,
                              void* d_out, int out_size, void* d_ws, size_t ws_size,
                              hipStream_t stream) {
    const float4* A = (const float4*)d_in[0];
    const int n = in_sizes[0] / 4;                    // 5,000,000 matrices
    const int nb1 = (n + TILE - 1) / TILE;            // 3907 block partials
    const int ng = (nb1 + 63) / 64;                   // 62 tail blocks

    // ws layout: part @0 (3907*32 = 125,024 B); gpart @131,072 (62*32 B);
    // cnt @135,168 (4 B).
    double*   part  = (double*)d_ws;
    double*   gpart = (double*)((char*)d_ws + 131072);
    unsigned* cnt   = (unsigned*)((char*)d_ws + 135168);

    hipMemsetAsync(cnt, 0, sizeof(unsigned), stream);
    prodchain_phase1<<<nb1, P1_TPB, 0, stream>>>(A, n, part);
    prodchain_tail<<<ng, 64, 0, stream>>>(part, nb1, ng, gpart, cnt,
                                          (float*)d_out);
}